// Round 1
// baseline (24.457 us; speedup 1.0000x reference)
//
#include <hip/hip_runtime.h>

#define B 16
#define T 2048
#define D 1024
#define TCHUNK 64
#define CHUNKS_PER_B (T / TCHUNK)   // 32

// Kernel 1 (1 block, 256 threads):
//  - softmax(weights[T]) -> scores in d_ws
//  - zero d_out (harness poisons it; main kernel accumulates atomically)
__global__ __launch_bounds__(256) void init_kernel(const float* __restrict__ weights,
                                                   float* __restrict__ scores,
                                                   float* __restrict__ out) {
    __shared__ float red[16];
    const int tid = threadIdx.x;
    const int wave = tid >> 6;

    // each thread handles 8 consecutive weights
    float w[8];
    float lmax = -3.4e38f;
#pragma unroll
    for (int i = 0; i < 8; ++i) {
        w[i] = weights[tid * 8 + i];
        lmax = fmaxf(lmax, w[i]);
    }
    // wave64 butterfly max
#pragma unroll
    for (int off = 32; off > 0; off >>= 1)
        lmax = fmaxf(lmax, __shfl_xor(lmax, off));
    if ((tid & 63) == 0) red[wave] = lmax;
    __syncthreads();
    const float gmax = fmaxf(fmaxf(red[0], red[1]), fmaxf(red[2], red[3]));

    float e[8];
    float lsum = 0.f;
#pragma unroll
    for (int i = 0; i < 8; ++i) {
        e[i] = expf(w[i] - gmax);
        lsum += e[i];
    }
#pragma unroll
    for (int off = 32; off > 0; off >>= 1)
        lsum += __shfl_xor(lsum, off);
    if ((tid & 63) == 0) red[8 + wave] = lsum;
    __syncthreads();
    const float inv = 1.f / (red[8] + red[9] + red[10] + red[11]);
#pragma unroll
    for (int i = 0; i < 8; ++i)
        scores[tid * 8 + i] = e[i] * inv;

    // zero out[B*D] = 16384 floats = 4096 float4
    float4* o4 = (float4*)out;
#pragma unroll
    for (int i = 0; i < 16; ++i)
        o4[i * 256 + tid] = make_float4(0.f, 0.f, 0.f, 0.f);
}

// Kernel 2: one block per (b, t-chunk). 256 threads x float4 = full D row.
// Skips chunks entirely past lengths[b] (masked rows are never fetched).
__global__ __launch_bounds__(256) void wsum_kernel(const float* __restrict__ input,
                                                   const int* __restrict__ lengths,
                                                   const float* __restrict__ scores,
                                                   float* __restrict__ out) {
    const int b = blockIdx.x >> 5;        // / CHUNKS_PER_B
    const int chunk = blockIdx.x & 31;    // % CHUNKS_PER_B
    const int t0 = chunk * TCHUNK;
    const int len = lengths[b];
    if (t0 >= len) return;                // fully masked chunk: no reads at all
    const int tend = min(t0 + TCHUNK, len);

    const int tid = threadIdx.x;
    const float4* __restrict__ in4 =
        (const float4*)input + ((size_t)b * T + (size_t)t0) * (D / 4) + tid;

    float4 acc = make_float4(0.f, 0.f, 0.f, 0.f);
#pragma unroll 4
    for (int t = t0; t < tend; ++t) {
        const float c = scores[t];        // block-uniform -> scalar load
        const float4 v = *in4;
        in4 += D / 4;
        acc.x = fmaf(c, v.x, acc.x);
        acc.y = fmaf(c, v.y, acc.y);
        acc.z = fmaf(c, v.z, acc.z);
        acc.w = fmaf(c, v.w, acc.w);
    }

    float* o = out + b * D + tid * 4;
    atomicAdd(o + 0, acc.x);
    atomicAdd(o + 1, acc.y);
    atomicAdd(o + 2, acc.z);
    atomicAdd(o + 3, acc.w);
}

extern "C" void kernel_launch(void* const* d_in, const int* in_sizes, int n_in,
                              void* d_out, int out_size, void* d_ws, size_t ws_size,
                              hipStream_t stream) {
    const float* input   = (const float*)d_in[0];
    const int*   lengths = (const int*)d_in[1];
    const float* weights = (const float*)d_in[2];
    float* out    = (float*)d_out;
    float* scores = (float*)d_ws;   // 2048 floats = 8 KB scratch

    init_kernel<<<1, 256, 0, stream>>>(weights, scores, out);
    wsum_kernel<<<B * CHUNKS_PER_B, 256, 0, stream>>>(input, lengths, scores, out);
}